// Round 6
// baseline (28226.202 us; speedup 1.0000x reference)
//
#include <hip/hip_runtime.h>
#include <hip/hip_bf16.h>

// ---------------------------------------------------------------------------
// LSTMTagger: char-LSTM (4096x16, H=128) -> word-LSTM (serial 4096, H=512)
//             -> linear(64) + log_softmax.
// Wire dtype of float tensors detected at runtime (bf16 vs f32); kernels
// dual-path on device flag ws[OFF_FLAG]: 1 = bf16, 0 = f32.
//
// Word LSTM (serial wall; R4 = 2.46 us/step, HBM-latency polls): team of 16
// WGs x 1024 thr elected onto ONE XCD via HW_REG_XCC_ID, so h exchange stays
// in that XCD's shared L2. Polls are workgroup-scope atomic_or RMWs with a
// runtime-opaque zero: all global atomics execute at L2 (L1 has no atomic
// path), giving L1-bypass + local-L2 hit without inline asm. A one-time
// coherence probe falls back to agent-scope atomics (R4 protocol, ~10 ms) if
// same-XCD visibility fails. h_hist dwords double as ready flags via 0xFF
// sentinel (h in (-1,1): 0xFFFFFFFF = -NaN unreachable). A sticky LDS dead
// flag bounds every spin: broken protocol => finite run + 12345 signature.
// ---------------------------------------------------------------------------

#define OFF_CTRLZ 0      // 8 ints, memset 0: [0]=ticket [1]=rank cnt [2]=probe done [3]=fallback [6]=opaque zero
#define OFF_CTRLS 8      // 20 ints, memset FF: [0]=target xcd [1..16]=probe slots
#define OFF_FLAG  28
#define OFF_CEMB  32
#define OFF_CWIH  8224
#define OFF_CBIH  40992
#define OFF_CBHH  41504
#define OFF_CWHH  42016
#define OFF_BIH   107552
#define OFF_BHH   109600
#define OFF_W1T   111648
#define OFF_CGE   144416
#define OFF_CH    209952
#define OFF_XP2   734240
#define OFF_HH    4928544

#define SENT 0xFFFFFFFFu
#define XCC_GETREG_IMM 63508   // id=20 (HW_REG_XCC_ID), offset=0, size=32

__device__ __forceinline__ float sigf(float x) { return 1.0f / (1.0f + __expf(-x)); }
__device__ __forceinline__ float tanh_f(float x) { return 2.0f * sigf(2.0f * x) - 1.0f; }
__device__ __forceinline__ float b2f_lo(unsigned u) { return __uint_as_float(u << 16); }
__device__ __forceinline__ float b2f_hi(unsigned u) { return __uint_as_float(u & 0xFFFF0000u); }

// L2-point read: atomic RMW (or with runtime-opaque zero). Executes at the
// local XCD L2, bypassing L1. oz is loaded from zeroed memory so the
// compiler cannot reduce the idempotent RMW to a cacheable plain load.
__device__ __forceinline__ unsigned l2_read(unsigned* p, unsigned oz) {
    return __hip_atomic_fetch_or(p, oz, __ATOMIC_RELAXED, __HIP_MEMORY_SCOPE_WORKGROUP);
}

// f32 add over DPP lane patterns (VALU pipe, no LDS)
template <int CTRL>
__device__ __forceinline__ float dpp_add(float x) {
    int t = __builtin_amdgcn_update_dpp(0, __float_as_int(x), CTRL, 0xF, 0xF, true);
    return x + __int_as_float(t);
}
// sum over each 16-lane DPP row: ror8, ror4, quad xor2, quad xor1
__device__ __forceinline__ float row16_sum(float x) {
    x = dpp_add<0x128>(x);
    x = dpp_add<0x124>(x);
    x = dpp_add<0x4E>(x);
    x = dpp_add<0xB1>(x);
    return x;
}

// ---- D0: dtype detect ----------------------------------------------------
__global__ void detect_kernel(const unsigned* __restrict__ w, int* __restrict__ flagp) {
    unsigned v = w[threadIdx.x];
    unsigned e = (v >> 7) & 0xFF;
    int inr = (e >= 100 && e <= 140) ? 1 : 0;
    unsigned long long m = __ballot(inr);
    if (threadIdx.x == 0) flagp[0] = (__popcll(m) >= 56) ? 1 : 0;
}

// ---- K0: (bf16|f32) -> f32 convert ---------------------------------------
__global__ void convf_kernel(const void* __restrict__ s, float* __restrict__ d,
                             int n, const int* __restrict__ flagp) {
    int i = blockIdx.x * 256 + threadIdx.x;
    if (i >= n) return;
    d[i] = flagp[0] ? __bfloat162float(((const __hip_bfloat16*)s)[i])
                    : ((const float*)s)[i];
}

// ---- K0b: W1 (64x512) -> W1T (512x64) f32 --------------------------------
__global__ void w1t_kernel(const void* __restrict__ W1, float* __restrict__ W1T,
                           const int* __restrict__ flagp) {
    int i = blockIdx.x * 256 + threadIdx.x;
    int j = i & 63, k = i >> 6;
    W1T[i] = flagp[0] ? __bfloat162float(((const __hip_bfloat16*)W1)[j * 512 + k])
                      : ((const float*)W1)[j * 512 + k];
}

// ---- K1: char gate table -------------------------------------------------
__global__ void __launch_bounds__(256) cge_kernel(
    const float* __restrict__ cemb, const float* __restrict__ cWih,
    const float* __restrict__ cbih, const float* __restrict__ cbhh,
    float* __restrict__ cge)
{
    __shared__ float xe[64];
    int c = blockIdx.x, tid = threadIdx.x;
    if (tid < 64) xe[tid] = cemb[c * 64 + tid];
    __syncthreads();
#pragma unroll
    for (int rep = 0; rep < 2; ++rep) {
        int j = rep * 256 + tid;
        float acc = cbih[j] + cbhh[j];
#pragma unroll 8
        for (int k = 0; k < 64; ++k)
            acc += xe[k] * cWih[j * 64 + k];
        cge[c * 512 + j] = acc;
    }
}

// ---- K2: char LSTM -------------------------------------------------------
__global__ void __launch_bounds__(256) char_lstm_kernel(
    const float* __restrict__ cge, const float* __restrict__ Whh,
    const int* __restrict__ chars, const int* __restrict__ lens,
    float* __restrict__ char_h)
{
    __shared__ float hls[16][128];
    int tid = threadIdx.x;
    int wl = tid >> 4, sl = tid & 15;
    int w = blockIdx.x * 16 + wl;
    int len = lens[w];
    const int* cw = chars + w * 16;
    float c[8];
#pragma unroll
    for (int q = 0; q < 8; ++q) { c[q] = 0.0f; hls[wl][sl * 8 + q] = 0.0f; }

    for (int t = 0; t < 16; ++t) {
        __syncthreads();
        int ch = cw[t];
        const float* xg = cge + ch * 512;
        float acc[4][8];
#pragma unroll
        for (int g = 0; g < 4; ++g)
#pragma unroll
            for (int q = 0; q < 8; ++q)
                acc[g][q] = xg[g * 128 + sl * 8 + q];

        const float4* h4 = (const float4*)hls[wl];
#pragma unroll
        for (int g = 0; g < 4; ++g) {
            const float4* wbase = ((const float4*)Whh) + (g * 128 + sl * 8) * 32;
            for (int k4 = 0; k4 < 32; ++k4) {
                float4 hv = h4[k4];
#pragma unroll
                for (int q = 0; q < 8; ++q) {
                    float4 wv = wbase[q * 32 + k4];
                    acc[g][q] += wv.x * hv.x + wv.y * hv.y + wv.z * hv.z + wv.w * hv.w;
                }
            }
        }
        __syncthreads();
        if (t < len) {
#pragma unroll
            for (int q = 0; q < 8; ++q) {
                float iv = sigf(acc[0][q]);
                float fv = sigf(acc[1][q]);
                float gv = tanh_f(acc[2][q]);
                float ov = sigf(acc[3][q]);
                c[q] = fv * c[q] + iv * gv;
                hls[wl][sl * 8 + q] = ov * tanh_f(c[q]);
            }
        }
    }
    __syncthreads();
#pragma unroll
    for (int q = 0; q < 8; ++q)
        char_h[w * 128 + sl * 8 + q] = hls[wl][sl * 8 + q];
}

// ---- K3: word x-part gates (bf16 out) ------------------------------------
__global__ void __launch_bounds__(256) xp2_kernel(
    const void* __restrict__ wemb, const int* __restrict__ x,
    const float* __restrict__ char_h, const void* __restrict__ Wraw,
    const float* __restrict__ bih, const float* __restrict__ bhh,
    __hip_bfloat16* __restrict__ xp2, const int* __restrict__ flagp)
{
    __shared__ float feat[16][384];
    int flag = flagp[0];
    int tid = threadIdx.x, tl = tid >> 4, sl = tid & 15;
    int t = blockIdx.x * 16 + tl;
    int xw = x[t];
    for (int idx = sl; idx < 384; idx += 16) {
        float v;
        if (idx < 256)
            v = flag ? __bfloat162float(((const __hip_bfloat16*)wemb)[(size_t)xw * 256 + idx])
                     : ((const float*)wemb)[(size_t)xw * 256 + idx];
        else
            v = char_h[t * 128 + (idx - 256)];
        feat[tl][idx] = v;
    }
    __syncthreads();

    const float4* f4 = (const float4*)feat[tl];
    for (int rb = 0; rb < 4; ++rb) {
        int r0 = rb * 512 + sl * 32;
        for (int qc = 0; qc < 4; ++qc) {
            int rr = r0 + qc * 8;
            float acc[8];
#pragma unroll
            for (int q = 0; q < 8; ++q)
                acc[q] = bih[rr + q] + bhh[rr + q];
            if (!flag) {
                const float4* wb = ((const float4*)Wraw) + (size_t)rr * 96;
                for (int k4 = 0; k4 < 96; ++k4) {
                    float4 fv = f4[k4];
#pragma unroll
                    for (int q = 0; q < 8; ++q) {
                        float4 wv = wb[q * 96 + k4];
                        acc[q] += wv.x * fv.x + wv.y * fv.y + wv.z * fv.z + wv.w * fv.w;
                    }
                }
            } else {
                const uint2* wb = ((const uint2*)Wraw) + (size_t)rr * 96;
                for (int k4 = 0; k4 < 96; ++k4) {
                    float4 fv = f4[k4];
#pragma unroll
                    for (int q = 0; q < 8; ++q) {
                        uint2 wv = wb[q * 96 + k4];
                        acc[q] += b2f_lo(wv.x) * fv.x + b2f_hi(wv.x) * fv.y
                                + b2f_lo(wv.y) * fv.z + b2f_hi(wv.y) * fv.w;
                    }
                }
            }
#pragma unroll
            for (int q = 0; q < 8; ++q)
                xp2[(size_t)t * 2048 + rr + q] = __float2bfloat16(acc[q]);
        }
    }
}

// ---- K5: serial word LSTM, XCD-local team, no-asm polls ------------------
// 16 team WGs x 1024 thr; rank owns slots [rank*32, rank*32+32).
// Thread (slot_local=tid>>5, p=tid&31): gp=p>>4 picks gate pair (i,f)/(g,o);
// kk=p&15 picks k-chunk [kk*32,+32). 64 weight f32 in VGPRs/thread.
__global__ void __launch_bounds__(1024, 4) word_lstm_kernel(
    const __hip_bfloat16* __restrict__ xp2, const void* __restrict__ Whh_raw,
    float* __restrict__ h_hist, const int* __restrict__ flagp,
    int* __restrict__ cz, unsigned* __restrict__ cs)
{
    __shared__ float hpad[2][576];   // 16 chunks x (32 + 4 pad)
    __shared__ float h_lds[32];
    __shared__ int step_flag;
    __shared__ int dead_flag;
    __shared__ int s_rank, s_mode;

    int tid = threadIdx.x;
    unsigned oz = (unsigned)cz[6];   // runtime-opaque zero (memset 0, never written)

    // ---- team election (device-scope, one-time) ----
    if (tid == 0) {
        int xcc = (int)(__builtin_amdgcn_s_getreg(XCC_GETREG_IMM) & 15u);
        int e = __hip_atomic_fetch_add(&cz[0], 1, __ATOMIC_RELAXED, __HIP_MEMORY_SCOPE_AGENT);
        if (e == 0)
            __hip_atomic_store(&cs[0], (unsigned)xcc, __ATOMIC_RELEASE, __HIP_MEMORY_SCOPE_AGENT);
        unsigned tgt; unsigned sp = 0;
        do { tgt = __hip_atomic_load(&cs[0], __ATOMIC_ACQUIRE, __HIP_MEMORY_SCOPE_AGENT); }
        while (tgt == SENT && ++sp < (1u << 20));
        int rank = -1;
        if (tgt != SENT && (unsigned)xcc == tgt) {
            rank = __hip_atomic_fetch_add(&cz[1], 1, __ATOMIC_RELAXED, __HIP_MEMORY_SCOPE_AGENT);
            if (rank >= 16) rank = -1;
        }
        s_rank = rank;
        dead_flag = 0;
    }
    __syncthreads();
    int rank = s_rank;
    if (rank < 0) return;

    // ---- coherence probe: plain store then L2-RMW read must see all 16
    // team slots. On timeout -> global fallback to agent-scope protocol. ----
    if (tid == 0) {
        __hip_atomic_store(&cs[1 + rank], 0xC0DE0000u + (unsigned)rank,
                           __ATOMIC_RELAXED, __HIP_MEMORY_SCOPE_WORKGROUP);
        int ok = 1;
        for (int r = 0; r < 16 && ok; ++r) {
            unsigned want = 0xC0DE0000u + (unsigned)r, v = 0; int sp2 = 0;
            do { v = l2_read(&cs[1 + r], oz); } while (v != want && ++sp2 < 20000);
            if (v != want) ok = 0;
        }
        if (!ok) __hip_atomic_fetch_or(&cz[3], 1, __ATOMIC_RELAXED, __HIP_MEMORY_SCOPE_AGENT);
        __hip_atomic_fetch_add(&cz[2], 1, __ATOMIC_RELEASE, __HIP_MEMORY_SCOPE_AGENT);
        unsigned sp3 = 0;
        while (__hip_atomic_load(&cz[2], __ATOMIC_ACQUIRE, __HIP_MEMORY_SCOPE_AGENT) < 16
               && ++sp3 < (1u << 20)) {}
        s_mode = (__hip_atomic_load(&cz[3], __ATOMIC_RELAXED, __HIP_MEMORY_SCOPE_AGENT) == 0) ? 1 : 0;
    }

    // ---- per-thread geometry + register-resident weights ----
    int flag = flagp[0];
    int wave = tid >> 6, lane = tid & 63;
    int slot_local = tid >> 5;
    int p = tid & 31;
    int gp = p >> 4, kk = p & 15;
    int slot = rank * 32 + slot_local;
    int r0 = (gp * 2) * 512 + slot;        // gate i (gp=0) / g (gp=1)
    int r1 = (gp * 2 + 1) * 512 + slot;    // gate f (gp=0) / o (gp=1)

    float4 w0[8], w1[8];
    if (!flag) {
        const float4* a = (const float4*)((const float*)Whh_raw + (size_t)r0 * 512 + kk * 32);
        const float4* b = (const float4*)((const float*)Whh_raw + (size_t)r1 * 512 + kk * 32);
#pragma unroll
        for (int i = 0; i < 8; ++i) { w0[i] = a[i]; w1[i] = b[i]; }
    } else {
        const uint2* a = (const uint2*)((const unsigned short*)Whh_raw + (size_t)r0 * 512 + kk * 32);
        const uint2* b = (const uint2*)((const unsigned short*)Whh_raw + (size_t)r1 * 512 + kk * 32);
#pragma unroll
        for (int i = 0; i < 8; ++i) {
            uint2 ua = a[i], ub = b[i];
            w0[i] = make_float4(b2f_lo(ua.x), b2f_hi(ua.x), b2f_lo(ua.y), b2f_hi(ua.y));
            w1[i] = make_float4(b2f_lo(ub.x), b2f_hi(ub.x), b2f_lo(ub.y), b2f_hi(ub.y));
        }
    }

    for (int i = tid; i < 576; i += 1024) hpad[0][i] = 0.0f;   // h_{-1} = 0
    if (tid == 0) step_flag = 0;
    __syncthreads();
    int l2mode = s_mode;

    unsigned* hview = (unsigned*)h_hist;
    float c = 0.0f;

    for (int t = 0; t < 4096; ++t) {
        float xv0 = __bfloat162float(xp2[(size_t)t * 2048 + r0]);   // h-independent
        float xv1 = __bfloat162float(xp2[(size_t)t * 2048 + r1]);

        // wait for hpad[t&1] = h_{t-1}; bounded, sticky-dead on timeout
        if (__hip_atomic_load(&dead_flag, __ATOMIC_RELAXED, __HIP_MEMORY_SCOPE_WORKGROUP) == 0) {
            unsigned ls = 0;
            while (__hip_atomic_load(&step_flag, __ATOMIC_ACQUIRE,
                                     __HIP_MEMORY_SCOPE_WORKGROUP) < t) {
                if (++ls > (1u << 22)) {
                    __hip_atomic_store(&dead_flag, 1, __ATOMIC_RELAXED, __HIP_MEMORY_SCOPE_WORKGROUP);
                    break;
                }
            }
        }

        const float4* h4 = (const float4*)(&hpad[t & 1][kk * 36]);
        float a0 = 0.0f, a1 = 0.0f;
#pragma unroll
        for (int i = 0; i < 8; ++i) {
            float4 hv = h4[i];
            a0 += w0[i].x * hv.x + w0[i].y * hv.y + w0[i].z * hv.z + w0[i].w * hv.w;
            a1 += w1[i].x * hv.x + w1[i].y * hv.y + w1[i].z * hv.z + w1[i].w * hv.w;
        }
        a0 = row16_sum(a0) + xv0;
        a1 = row16_sum(a1) + xv1;
        float o0 = __shfl_xor(a0, 16);
        float o1 = __shfl_xor(a1, 16);
        float iv = gp ? o0 : a0;
        float fv = gp ? o1 : a1;
        float gg = gp ? a0 : o0;
        float ov = gp ? a1 : o1;
        c = sigf(fv) * c + sigf(iv) * tanh_f(gg);
        float h = sigf(ov) * tanh_f(c);

        if (p == 0) h_lds[slot_local] = h;
        __syncthreads();   // h_lds complete; hpad[t&1] reads done

        if (wave == 0) {
            // ONE coalesced 128B store for this WG's 32-slot chunk
            if (lane < 32) {
                unsigned hv = __float_as_uint(h_lds[lane]);
                unsigned* dstp = hview + (size_t)t * 512 + rank * 32 + lane;
                if (l2mode)
                    __hip_atomic_store(dstp, hv, __ATOMIC_RELAXED, __HIP_MEMORY_SCOPE_WORKGROUP);
                else
                    __hip_atomic_store(dstp, hv, __ATOMIC_RELAXED, __HIP_MEMORY_SCOPE_AGENT);
            }
            if (t < 4095) {
                unsigned v[8];
                if ((lane >> 2) == rank) {
                    // own chunk straight from LDS
#pragma unroll
                    for (int i = 0; i < 8; ++i)
                        v[i] = __float_as_uint(h_lds[(lane & 3) * 8 + i]);
                } else {
                    int deadv = __hip_atomic_load(&dead_flag, __ATOMIC_RELAXED,
                                                  __HIP_MEMORY_SCOPE_WORKGROUP);
                    bool bail = (deadv != 0);
                    if (!bail) {
                        unsigned* src = hview + (size_t)t * 512 + lane * 8;
                        unsigned spins = 0;
                        if (l2mode) {
                            for (;;) {
#pragma unroll
                                for (int i = 0; i < 8; ++i)
                                    v[i] = l2_read(src + i, oz);
                                int ok = 1;
#pragma unroll
                                for (int i = 0; i < 8; ++i) ok &= (v[i] != SENT);
                                if (ok) break;                       // per-lane exit
                                if (++spins > (1u << 16)) { bail = true; break; }
                            }
                        } else {
                            for (;;) {
#pragma unroll
                                for (int i = 0; i < 8; ++i)
                                    v[i] = __hip_atomic_load(src + i, __ATOMIC_RELAXED,
                                                             __HIP_MEMORY_SCOPE_AGENT);
                                int ok = 1;
#pragma unroll
                                for (int i = 0; i < 8; ++i) ok &= (v[i] != SENT);
                                if (ok) break;
                                if (++spins > (1u << 16)) { bail = true; break; }
                            }
                        }
                    }
                    if (bail) {
                        __hip_atomic_store(&dead_flag, 1, __ATOMIC_RELAXED,
                                           __HIP_MEMORY_SCOPE_WORKGROUP);
#pragma unroll
                        for (int i = 0; i < 8; ++i) v[i] = __float_as_uint(12345.0f);
                    }
                }
                float* dst = &hpad[(t + 1) & 1][(lane >> 2) * 36 + (lane & 3) * 8];
                ((float4*)dst)[0] = make_float4(__uint_as_float(v[0]), __uint_as_float(v[1]),
                                                __uint_as_float(v[2]), __uint_as_float(v[3]));
                ((float4*)dst)[1] = make_float4(__uint_as_float(v[4]), __uint_as_float(v[5]),
                                                __uint_as_float(v[6]), __uint_as_float(v[7]));
                __hip_atomic_store(&step_flag, t + 1, __ATOMIC_RELEASE,
                                   __HIP_MEMORY_SCOPE_WORKGROUP);
            }
        }
    }
}

// ---- K6: logits + log_softmax. 64 blocks x 256 thr; W1 staged in LDS as
//          packed bf16 pairs. -----------------------------------------------
__global__ void __launch_bounds__(256) out_kernel(
    const float* __restrict__ h_hist, const float* __restrict__ W1T,
    const void* __restrict__ b1raw, void* __restrict__ out,
    const int* __restrict__ flagp)
{
    __shared__ unsigned wlds[128 * 64];   // 32 KB: (k-pair q, j) packed 2xbf16
    __shared__ float hb[4][256];
    int flagv = flagp[0];
    int tid = threadIdx.x, wv = tid >> 6, j = tid & 63;
    int t0 = blockIdx.x * 64 + wv * 16;

    float bj = flagv ? __bfloat162float(((const __hip_bfloat16*)b1raw)[j])
                     : ((const float*)b1raw)[j];
    float acc[16];
#pragma unroll
    for (int i = 0; i < 16; ++i) acc[i] = bj;

    for (int pass = 0; pass < 2; ++pass) {
        __syncthreads();
        for (int i = tid; i < 128 * 64; i += 256) {
            int q = i >> 6, j2 = i & 63;
            int k = pass * 256 + q * 2;
            unsigned lo = (__float_as_uint(W1T[k * 64 + j2]) + 0x8000u) >> 16;
            unsigned hi = (__float_as_uint(W1T[(k + 1) * 64 + j2]) + 0x8000u) & 0xFFFF0000u;
            wlds[i] = hi | lo;
        }
        __syncthreads();
        for (int ti = 0; ti < 16; ++ti) {
            int t = t0 + ti;
            const float4* hsrc = (const float4*)(h_hist + (size_t)t * 512 + pass * 256);
            ((float4*)hb[wv])[j] = hsrc[j];
            __syncthreads();   // cross-lane LDS visibility (uniform trip count)
            float a = acc[ti];
            const float2* hb2 = (const float2*)hb[wv];
#pragma unroll 16
            for (int q = 0; q < 128; ++q) {
                float2 hv = hb2[q];
                unsigned wp = wlds[q * 64 + j];
                a += b2f_lo(wp) * hv.x + b2f_hi(wp) * hv.y;
            }
            acc[ti] = a;
            __syncthreads();   // reads done before next ti overwrites hb
        }
    }

#pragma unroll
    for (int ti = 0; ti < 16; ++ti) {
        int t = t0 + ti;
        float a = acc[ti];
        float m = a;
        for (int o = 32; o; o >>= 1) m = fmaxf(m, __shfl_xor(m, o));
        float e = __expf(a - m), s = e;
        for (int o = 32; o; o >>= 1) s += __shfl_xor(s, o);
        float r = a - m - __logf(s);
        if (flagv) ((__hip_bfloat16*)out)[t * 64 + j] = __float2bfloat16(r);
        else       ((float*)out)[t * 64 + j] = r;
    }
}

extern "C" void kernel_launch(void* const* d_in, const int* in_sizes, int n_in,
                              void* d_out, int out_size, void* d_ws, size_t ws_size,
                              hipStream_t stream)
{
    (void)in_sizes; (void)n_in; (void)out_size; (void)ws_size;
    const void* char_emb = d_in[0];
    const void* char_Wih = d_in[1];
    const void* char_Whh = d_in[2];
    const void* char_bih = d_in[3];
    const void* char_bhh = d_in[4];
    const void* word_emb = d_in[5];
    const void* Wih      = d_in[6];
    const void* Whh      = d_in[7];
    const void* bih      = d_in[8];
    const void* bhh      = d_in[9];
    const void* W1       = d_in[10];
    const void* b1       = d_in[11];
    const int* x     = (const int*)d_in[12];
    const int* chars = (const int*)d_in[13];
    const int* lens  = (const int*)d_in[14];

    float* ws    = (float*)d_ws;
    int*      cz = (int*)(ws + OFF_CTRLZ);
    unsigned* cs = (unsigned*)(ws + OFF_CTRLS);
    int*   flagp = (int*)(ws + OFF_FLAG);
    float* cembf = ws + OFF_CEMB;
    float* cWihf = ws + OFF_CWIH;
    float* cbihf = ws + OFF_CBIH;
    float* cbhhf = ws + OFF_CBHH;
    float* cWhhf = ws + OFF_CWHH;
    float* bihf  = ws + OFF_BIH;
    float* bhhf  = ws + OFF_BHH;
    float* W1T   = ws + OFF_W1T;
    float* cge   = ws + OFF_CGE;
    float* charh = ws + OFF_CH;
    __hip_bfloat16* xp2 = (__hip_bfloat16*)(ws + OFF_XP2);
    float* hh    = ws + OFF_HH;

    hipMemsetAsync(cz, 0, 8 * 4, stream);
    hipMemsetAsync(cs, 0xFF, 20 * 4, stream);
    hipMemsetAsync(hh, 0xFF, (size_t)4096 * 512 * 4, stream);

    detect_kernel<<<1, 64, 0, stream>>>((const unsigned*)char_emb, flagp);

    convf_kernel<<<(8192 + 255) / 256, 256, 0, stream>>>(char_emb, cembf, 8192, flagp);
    convf_kernel<<<(32768 + 255) / 256, 256, 0, stream>>>(char_Wih, cWihf, 32768, flagp);
    convf_kernel<<<2, 256, 0, stream>>>(char_bih, cbihf, 512, flagp);
    convf_kernel<<<2, 256, 0, stream>>>(char_bhh, cbhhf, 512, flagp);
    convf_kernel<<<(65536 + 255) / 256, 256, 0, stream>>>(char_Whh, cWhhf, 65536, flagp);
    convf_kernel<<<8, 256, 0, stream>>>(bih, bihf, 2048, flagp);
    convf_kernel<<<8, 256, 0, stream>>>(bhh, bhhf, 2048, flagp);
    w1t_kernel<<<128, 256, 0, stream>>>(W1, W1T, flagp);

    cge_kernel<<<128, 256, 0, stream>>>(cembf, cWihf, cbihf, cbhhf, cge);
    char_lstm_kernel<<<256, 256, 0, stream>>>(cge, cWhhf, chars, lens, charh);
    xp2_kernel<<<256, 256, 0, stream>>>(word_emb, x, charh, Wih, bihf, bhhf, xp2, flagp);
    word_lstm_kernel<<<256, 1024, 0, stream>>>(xp2, Whh, hh, flagp, cz, cs);
    out_kernel<<<64, 256, 0, stream>>>(hh, W1T, b1, d_out, flagp);
}